// Round 11
// baseline (2464.396 us; speedup 1.0000x reference)
//
#include <hip/hip_runtime.h>
#include <math.h>

// Problem constants
#define B_   32
#define S_   32
#define N_   512
#define D_   16
#define H_   64
#define EPS_ 1e-5f
#define CNT_ 16384.0f     // B*N samples per batchnorm channel
#define SNH_ 1048576      // S*N*H (per-batch feats stride)
#define NH_  32768        // N*H
#define LDST 72           // padded LDS row stride (fp16 elems)

typedef __attribute__((ext_vector_type(8))) short short8v;
typedef __attribute__((ext_vector_type(8))) _Float16 f16x8;
typedef __attribute__((ext_vector_type(4))) float f32x4;

__device__ __forceinline__ float sigm(float x) { return 1.0f / (1.0f + __expf(-x)); }

__device__ __forceinline__ unsigned short f2h(float x) {
  union { _Float16 h; unsigned short u; } c;
  c.h = (_Float16)x;
  return c.u;
}
__device__ __forceinline__ float h2f(unsigned short u) {
  union { _Float16 h; unsigned short u; } c;
  c.u = u;
  return (float)c.h;
}
// load 8 contiguous fp16 -> 8 floats
__device__ __forceinline__ void ld8h(const unsigned short* p, float* o) {
  f16x8 v = *(const f16x8*)p;
#pragma unroll
  for (int i = 0; i < 8; ++i) o[i] = (float)v[i];
}
// store 8 floats -> 8 contiguous fp16
__device__ __forceinline__ void st8h(unsigned short* p, const float* v) {
  short8v o;
#pragma unroll
  for (int i = 0; i < 8; ++i) ((unsigned short*)&o)[i] = f2h(v[i]);
  *(short8v*)p = o;
}

// ---------------------------------------------------------------------------
// Setup: degree factors from incidence H (512x128)
// ---------------------------------------------------------------------------
__global__ __launch_bounds__(256) void k_deg(const float* __restrict__ Hm,
                                             float* __restrict__ Hs,
                                             float* __restrict__ Hd) {
  __shared__ float sdv[512];
  __shared__ float sde[128];
  __shared__ float tmp[256];
  const int tid = threadIdx.x;
  const int e = tid & 127, half = tid >> 7;
  float p = 0.f;
  for (int r = 0; r < 256; ++r) p += Hm[(half * 256 + r) * 128 + e];
  tmp[tid] = p;
  for (int n = tid; n < 512; n += 256) {
    float s = 0.f;
    for (int k = 0; k < 128; k += 4) {
      float4 v = *(const float4*)&Hm[n * 128 + k];
      s += v.x + v.y + v.z + v.w;
    }
    sdv[n] = s;
  }
  __syncthreads();
  if (tid < 128) sde[tid] = tmp[tid] + tmp[tid + 128];
  __syncthreads();
  for (int i = tid; i < 512 * 128; i += 256) {
    int n = i >> 7, ee = i & 127;
    float hv = Hm[i];
    float hs = hv * rsqrtf(sdv[n]);
    Hs[i] = hs;
    Hd[i] = hs / sde[ee];
  }
}

// ---------------------------------------------------------------------------
// Setup: Gh (fp16) = Hd @ Hs^T  (512x512, K=128) — direct fp16 store.
// ---------------------------------------------------------------------------
__global__ __launch_bounds__(256) void g_build(const float* __restrict__ A,
                                               const float* __restrict__ B,
                                               unsigned short* __restrict__ Gh) {
  constexpr int KT = 16;
  __shared__ float As[KT][64];
  __shared__ float Bs[KT][64];
  const int tid = threadIdx.x;
  const int tx = tid & 15, ty = tid >> 4;
  const int n0 = blockIdx.x * 64, m0 = blockIdx.y * 64;
  float acc[4][4];
#pragma unroll
  for (int i = 0; i < 4; ++i)
#pragma unroll
    for (int j = 0; j < 4; ++j) acc[i][j] = 0.f;
  const int ra = tid >> 2, ca = (tid & 3) * 4;
  for (int k0 = 0; k0 < 128; k0 += KT) {
    {
      float4 v = *(const float4*)&A[(size_t)(m0 + ra) * 128 + k0 + ca];
      As[ca + 0][ra] = v.x; As[ca + 1][ra] = v.y;
      As[ca + 2][ra] = v.z; As[ca + 3][ra] = v.w;
    }
    {
      float4 v = *(const float4*)&B[(size_t)(n0 + ra) * 128 + k0 + ca];
      Bs[ca + 0][ra] = v.x; Bs[ca + 1][ra] = v.y;
      Bs[ca + 2][ra] = v.z; Bs[ca + 3][ra] = v.w;
    }
    __syncthreads();
#pragma unroll
    for (int kk = 0; kk < KT; ++kk) {
      float a[4], bv[4];
#pragma unroll
      for (int i = 0; i < 4; ++i) a[i] = As[kk][ty * 4 + i];
#pragma unroll
      for (int j = 0; j < 4; ++j) bv[j] = Bs[kk][tx * 4 + j];
#pragma unroll
      for (int i = 0; i < 4; ++i)
#pragma unroll
        for (int j = 0; j < 4; ++j) acc[i][j] = fmaf(a[i], bv[j], acc[i][j]);
    }
    __syncthreads();
  }
#pragma unroll
  for (int i = 0; i < 4; ++i)
#pragma unroll
    for (int j = 0; j < 4; ++j)
      Gh[(size_t)(m0 + ty * 4 + i) * 512 + n0 + tx * 4 + j] = f2h(acc[i][j]);
}

// ---------------------------------------------------------------------------
// fp16 MFMA GEMM: C[row][col] = sum_m A[row][m] * B[col][m].  C stored fp16.
// A = Gh (512x512), B = [col][m] fp16 (X^T). BM=128, BN=64, BK=64, 4 waves.
// Epilogue: fp16 C + per-channel BN sum/sumsq atomics (from f32 acc):
//   base = (colblk >= dirColblks) ? dirBase : 0 ; ch = col & chmask
// ---------------------------------------------------------------------------
__global__ __launch_bounds__(256) void gmfma(
    const unsigned short* __restrict__ A, const unsigned short* __restrict__ Bf,
    unsigned short* __restrict__ C, int Nt, float* __restrict__ stats,
    int chmask, int dirColblks, int dirBase, int sqOff) {
  __shared__ __align__(16) unsigned short As[128 * LDST];
  __shared__ __align__(16) unsigned short Bs[64 * LDST];
  const int tid = threadIdx.x;
  const int lane = tid & 63;
  const int w = tid >> 6, wr = w >> 1, wc = w & 1;
  const int l15 = lane & 15, l4 = lane >> 4;
  const int col0 = blockIdx.x * 64, n0 = blockIdx.y * 128;
  const int srow = tid >> 3, sch = (tid & 7) * 8;

  f32x4 acc[4][2];
#pragma unroll
  for (int mi = 0; mi < 4; ++mi)
#pragma unroll
    for (int ni = 0; ni < 2; ++ni) acc[mi][ni] = (f32x4)0.f;

  short8v pa[4], pb[2];
#pragma unroll
  for (int q = 0; q < 4; ++q)
    pa[q] = *(const short8v*)&A[(size_t)(n0 + srow + q * 32) * 512 + sch];
#pragma unroll
  for (int q = 0; q < 2; ++q)
    pb[q] = *(const short8v*)&Bf[(size_t)(col0 + srow + q * 32) * 512 + sch];

  for (int k0 = 0; k0 < 512; k0 += 64) {
#pragma unroll
    for (int q = 0; q < 4; ++q)
      *(short8v*)&As[(srow + q * 32) * LDST + sch] = pa[q];
#pragma unroll
    for (int q = 0; q < 2; ++q)
      *(short8v*)&Bs[(srow + q * 32) * LDST + sch] = pb[q];
    __syncthreads();
    if (k0 < 448) {
      int kn = k0 + 64;
#pragma unroll
      for (int q = 0; q < 4; ++q)
        pa[q] = *(const short8v*)&A[(size_t)(n0 + srow + q * 32) * 512 + kn + sch];
#pragma unroll
      for (int q = 0; q < 2; ++q)
        pb[q] = *(const short8v*)&Bf[(size_t)(col0 + srow + q * 32) * 512 + kn + sch];
    }
#pragma unroll
    for (int kk = 0; kk < 64; kk += 32) {
      f16x8 av[4], bv[2];
#pragma unroll
      for (int mi = 0; mi < 4; ++mi)
        av[mi] = *(const f16x8*)&As[(wr * 64 + mi * 16 + l15) * LDST + kk + l4 * 8];
#pragma unroll
      for (int ni = 0; ni < 2; ++ni)
        bv[ni] = *(const f16x8*)&Bs[(wc * 32 + ni * 16 + l15) * LDST + kk + l4 * 8];
#pragma unroll
      for (int mi = 0; mi < 4; ++mi)
#pragma unroll
        for (int ni = 0; ni < 2; ++ni)
          acc[mi][ni] = __builtin_amdgcn_mfma_f32_16x16x32_f16(av[mi], bv[ni],
                                                               acc[mi][ni], 0, 0, 0);
    }
    __syncthreads();
  }

  float cs[2] = {0.f, 0.f}, cq[2] = {0.f, 0.f};
#pragma unroll
  for (int mi = 0; mi < 4; ++mi)
#pragma unroll
    for (int ni = 0; ni < 2; ++ni)
#pragma unroll
      for (int r = 0; r < 4; ++r) {
        float val = acc[mi][ni][r];
        C[(size_t)(n0 + wr * 64 + mi * 16 + l4 * 4 + r) * Nt + col0 + wc * 32 + ni * 16 + l15] = f2h(val);
        cs[ni] += val;
        cq[ni] = fmaf(val, val, cq[ni]);
      }
  float* red = (float*)As;
  const int owner = wr * 4 + l4;
#pragma unroll
  for (int ni = 0; ni < 2; ++ni) {
    int cb = wc * 32 + ni * 16 + l15;
    red[cb * 8 + owner] = cs[ni];
    red[512 + cb * 8 + owner] = cq[ni];
  }
  __syncthreads();
  if (tid < 64) {
    float s = 0.f, q = 0.f;
    for (int o = 0; o < 8; ++o) { s += red[tid * 8 + o]; q += red[512 + tid * 8 + o]; }
    int base = (blockIdx.x >= dirColblks) ? dirBase : 0;
    int ch = (col0 + tid) & chmask;
    atomicAdd(&stats[base + ch], s);
    atomicAdd(&stats[base + sqOff + ch], q);
  }
}

// ---------------------------------------------------------------------------
// Pre: zero h (fp16), st1a, sto; X1(t0) = x @ W1[0:16] (h=0). Dual write fp16:
// col-major Xf1[col=dirb*128+d][m] + row-major Xr1A[(dirb*512+m)][d].
// ---------------------------------------------------------------------------
__global__ __launch_bounds__(512) void prek(
    const float* __restrict__ inp, const float* __restrict__ W1,
    unsigned short* __restrict__ Xf1, unsigned short* __restrict__ Xr1A,
    unsigned short* __restrict__ Xh, float* __restrict__ st1a,
    float* __restrict__ sto) {
  __shared__ float As[64 * 16];
  __shared__ float Ws[16 * 128];
  const int tid = threadIdx.x, bid = blockIdx.x;
  const int dirb = bid >> 3, m0 = (bid & 7) * 64;
  const int b = dirb & 31;
  const int t0 = (dirb < 32) ? 0 : (S_ - 1);
  *(short8v*)&Xh[((size_t)dirb * 512 + m0) * 64 + tid * 8] = (short8v)0;
  if (bid == 0) st1a[tid] = 0.f;
  if (bid == 1 && tid < 256) sto[tid] = 0.f;
  *(float4*)&Ws[tid * 4] = *(const float4*)&W1[tid * 4];
  {
    int row = tid >> 3, j = tid & 7;
    float2 iv = *(const float2*)&inp[(size_t)((b * S_ + t0) * N_ + m0 + row) * D_ + j * 2];
    As[row * 16 + j * 2] = iv.x;
    As[row * 16 + j * 2 + 1] = iv.y;
  }
  __syncthreads();
  const int tx = tid & 31, ty = tid >> 5;
  float acc[4][4];
#pragma unroll
  for (int i = 0; i < 4; ++i)
#pragma unroll
    for (int j = 0; j < 4; ++j) acc[i][j] = 0.f;
  for (int k = 0; k < 16; ++k) {
    float av[4];
#pragma unroll
    for (int i = 0; i < 4; ++i) av[i] = As[(ty * 4 + i) * 16 + k];
    float4 bv = *(const float4*)&Ws[k * 128 + tx * 4];
    float bva[4] = {bv.x, bv.y, bv.z, bv.w};
#pragma unroll
    for (int i = 0; i < 4; ++i)
#pragma unroll
      for (int j = 0; j < 4; ++j) acc[i][j] = fmaf(av[i], bva[j], acc[i][j]);
  }
#pragma unroll
  for (int j = 0; j < 4; ++j) {
    int g = dirb * 128 + tx * 4 + j;
    ushort4 o;
    o.x = f2h(acc[0][j]); o.y = f2h(acc[1][j]);
    o.z = f2h(acc[2][j]); o.w = f2h(acc[3][j]);
    *(ushort4*)&Xf1[(size_t)g * 512 + m0 + ty * 4] = o;
  }
#pragma unroll
  for (int i = 0; i < 4; ++i) {
    ushort4 o;
    o.x = f2h(acc[i][0]); o.y = f2h(acc[i][1]);
    o.z = f2h(acc[i][2]); o.w = f2h(acc[i][3]);
    *(ushort4*)&Xr1A[((size_t)dirb * 512 + m0 + ty * 4 + i) * 128 + tx * 4] = o;
  }
}

// ---------------------------------------------------------------------------
// cat2: X2 = cat(x_t, r*h) @ W2 with fused r-gate. Both dirs batched.
// h fp16 (Xh); residual x1 from row-major Xr1C. Dual write X2 (Xf2 + Xr2).
// ---------------------------------------------------------------------------
__global__ __launch_bounds__(512) void cat2k(
    const float* __restrict__ inp, const unsigned short* __restrict__ Xh,
    const float* __restrict__ W2, unsigned short* __restrict__ Xf2,
    unsigned short* __restrict__ Xr2,
    const unsigned short* __restrict__ G1h, const unsigned short* __restrict__ Xr1C,
    const float* __restrict__ st1c, const float* __restrict__ g1,
    const float* __restrict__ e1, const float* __restrict__ b1,
    float* __restrict__ st2, int tf, int tb) {
  __shared__ float As[80 * 64];     // [k][row]
  __shared__ float Ws[80 * 64];
  __shared__ float sm[128], sa[128], sb[128], sbb[128];
  const int tid = threadIdx.x, bid = blockIdx.x;
  const int dirb = bid >> 3, m0 = (bid & 7) * 64;
  const int b = dirb & 31;
  const int dir = (dirb >= 32);
  const int t = dir ? tb : tf;
  if (bid == 0 && tid < 256) st2[tid] = 0.f;
  const float* stp = st1c + (dir ? 256 : 0);
  if (tid < 128) {
    float mean = stp[tid] * (1.f / CNT_);
    float var = fmaf(stp[128 + tid], 1.f / CNT_, -mean * mean);
    float inv = rsqrtf(var + EPS_);
    sm[tid] = mean; sa[tid] = inv * g1[tid];
    sb[tid] = e1[tid]; sbb[tid] = b1[tid];
  }
  for (int i = tid * 4; i < 5120; i += 2048)
    *(float4*)&Ws[i] = *(const float4*)&W2[i];
  __syncthreads();
  const int row = tid >> 3, j = tid & 7;
  const int m = m0 + row;
  if (j < 4) {
    float4 iv = *(const float4*)&inp[(size_t)((b * S_ + t) * N_ + m) * D_ + j * 4];
    As[(j * 4 + 0) * 64 + row] = iv.x; As[(j * 4 + 1) * 64 + row] = iv.y;
    As[(j * 4 + 2) * 64 + row] = iv.z; As[(j * 4 + 3) * 64 + row] = iv.w;
  }
  {
    const int c0 = j * 8;
    const int n = m >> 1;
    const int dd = ((m & 1) << 6) + c0;
    float hva[8], gva[8], xva[8];
    ld8h(&Xh[((size_t)dirb * 512 + m) * 64 + c0], hva);
    ld8h(&G1h[(size_t)n * 8192 + dirb * 128 + dd], gva);
    ld8h(&Xr1C[((size_t)dirb * 512 + n) * 128 + dd], xva);
#pragma unroll
    for (int i = 0; i < 8; ++i) {
      int d2 = dd + i;
      float pre = fmaf(gva[i] - sm[d2], sa[d2], sb[d2]);
      pre = fmaxf(pre, 0.f) + xva[i] + sbb[d2];
      As[(16 + c0 + i) * 64 + row] = sigm(pre) * hva[i];
    }
  }
  __syncthreads();
  const int tx = tid & 15, ty = tid >> 4;
  float acc[2][4];
#pragma unroll
  for (int i = 0; i < 2; ++i)
#pragma unroll
    for (int jj = 0; jj < 4; ++jj) acc[i][jj] = 0.f;
  for (int k = 0; k < 80; ++k) {
    float a0 = As[k * 64 + ty * 2], a1 = As[k * 64 + ty * 2 + 1];
    float4 bv = *(const float4*)&Ws[k * 64 + tx * 4];
    float bva[4] = {bv.x, bv.y, bv.z, bv.w};
#pragma unroll
    for (int jj = 0; jj < 4; ++jj) {
      acc[0][jj] = fmaf(a0, bva[jj], acc[0][jj]);
      acc[1][jj] = fmaf(a1, bva[jj], acc[1][jj]);
    }
  }
#pragma unroll
  for (int jj = 0; jj < 4; ++jj) {
    int g = dirb * 64 + tx * 4 + jj;
    ushort2 o;
    o.x = f2h(acc[0][jj]); o.y = f2h(acc[1][jj]);
    *(ushort2*)&Xf2[(size_t)g * 512 + m0 + ty * 2] = o;
  }
#pragma unroll
  for (int i = 0; i < 2; ++i) {
    ushort4 o;
    o.x = f2h(acc[i][0]); o.y = f2h(acc[i][1]);
    o.z = f2h(acc[i][2]); o.w = f2h(acc[i][3]);
    *(ushort4*)&Xr2[((size_t)dirb * 512 + m0 + ty * 2 + i) * 64 + tx * 4] = o;
  }
}

// ---------------------------------------------------------------------------
// elt: gates + h update (fp16) + [fwd] feats0 write (f32) + out-proj column
// store (fp16) + X1(nextT) projection (Xf1 col-major + Xr1N row-major).
// ---------------------------------------------------------------------------
__global__ __launch_bounds__(512) void eltk(
    const float* __restrict__ inp, const unsigned short* __restrict__ G1h,
    const unsigned short* __restrict__ Xr1C, const float* __restrict__ st1c,
    const float* __restrict__ g1, const float* __restrict__ e1,
    const float* __restrict__ b1, const unsigned short* __restrict__ G2h,
    const unsigned short* __restrict__ Xr2, const float* __restrict__ st2,
    const float* __restrict__ g2, const float* __restrict__ e2,
    const float* __restrict__ b2, unsigned short* __restrict__ Xh,
    float* __restrict__ out1, const float* __restrict__ W1,
    unsigned short* __restrict__ Xf1, unsigned short* __restrict__ Xr1N,
    const float* __restrict__ W0o, const float* __restrict__ W1o,
    unsigned short* __restrict__ Xo16,
    int tf, int tb, int doX1, float* __restrict__ stn) {
  __shared__ float As[64 * 80];     // [row][k]: k<16 x_next, k>=16 hn
  __shared__ float Ws[80 * 128];
  __shared__ float sW0[128], sW1[128];
  const int tid = threadIdx.x, bid = blockIdx.x;
  const int dirb = bid >> 3, m0 = (bid & 7) * 64;
  const int b = dirb & 31;
  const int dir = (dirb >= 32);
  const int t = dir ? tb : tf;
  const int nextT = dir ? (tb - 1) : (tf + 1);
  if (bid == 0) stn[tid] = 0.f;
  if (tid < 128) { sW0[tid] = W0o[tid]; sW1[tid] = W1o[tid]; }
  __syncthreads();

  const int row = tid >> 3, co = (tid & 7) * 8;
  const int m = m0 + row;
  const int mh = m >> 1;
  const int du0 = ((m & 1) << 6) + co;
  const float* stp = st1c + (dir ? 256 : 0);
  const float* st2p = st2 + (dir ? 128 : 0);
  float g1a[8], g2a[8], ha[8], x1a[8], x2a[8];
  {
    ld8h(&Xh[((size_t)dirb * 512 + m) * 64 + co], ha);
    ld8h(&G1h[(size_t)(256 + mh) * 8192 + dirb * 128 + du0], g1a);
    ld8h(&G2h[(size_t)m * 4096 + dirb * 64 + co], g2a);
    ld8h(&Xr1C[((size_t)dirb * 512 + 256 + mh) * 128 + du0], x1a);
    ld8h(&Xr2[((size_t)dirb * 512 + m) * 64 + co], x2a);
  }
  float hn[8];
#pragma unroll
  for (int i = 0; i < 8; ++i) {
    int du = du0 + i;
    float mean = stp[du] * (1.f / CNT_);
    float var = stp[128 + du] * (1.f / CNT_) - mean * mean;
    float inv = rsqrtf(var + EPS_);
    float pre = fmaxf((g1a[i] - mean) * inv * g1[du] + e1[du], 0.f) + x1a[i] + b1[du];
    float u = sigm(pre);
    int dc = co + i;
    float mean2 = st2p[dc] * (1.f / CNT_);
    float var2 = st2p[64 + dc] * (1.f / CNT_) - mean2 * mean2;
    float inv2 = rsqrtf(var2 + EPS_);
    float pre2 = fmaxf((g2a[i] - mean2) * inv2 * g2[dc] + e2[dc], 0.f) + x2a[i] + b2[dc];
    float cc = tanhf(pre2);
    hn[i] = u * ha[i] + (1.f - u) * cc;
  }
  st8h(&Xh[((size_t)dirb * 512 + m) * 64 + co], hn);
  *(float4*)&As[row * 80 + 16 + co] = *(const float4*)&hn[0];
  *(float4*)&As[row * 80 + 16 + co + 4] = *(const float4*)&hn[4];
  if (!dir) {  // fwd: feats0 (f32 exact)
    float* po = &out1[(size_t)b * SNH_ + (size_t)t * NH_ + m * 64 + co];
    *(float4*)&po[0] = *(const float4*)&hn[0];
    *(float4*)&po[4] = *(const float4*)&hn[4];
  }
  {
    const float* sW = dir ? sW1 : sW0;
    float p0 = 0.f, p1 = 0.f;
#pragma unroll
    for (int jj = 0; jj < 8; ++jj) {
      int c = co + jj;
      p0 = fmaf(hn[jj], sW[c * 2], p0);
      p1 = fmaf(hn[jj], sW[c * 2 + 1], p1);
    }
#pragma unroll
    for (int off = 1; off < 8; off <<= 1) {
      p0 += __shfl_xor(p0, off);
      p1 += __shfl_xor(p1, off);
    }
    if ((tid & 7) == 0) {
      int colb = (dir ? 2048 : 0) + b * 64 + t * 2;
      Xo16[(size_t)colb * 512 + m] = f2h(p0);
      Xo16[(size_t)(colb + 1) * 512 + m] = f2h(p1);
    }
  }

  if (doX1) {
    {
      int ri = tid >> 3, k2 = (tid & 7) * 2;
      float2 iv = *(const float2*)&inp[(size_t)((b * S_ + nextT) * N_ + m0 + ri) * D_ + k2];
      As[ri * 80 + k2] = iv.x;
      As[ri * 80 + k2 + 1] = iv.y;
    }
    for (int i = tid * 4; i < 10240; i += 2048)
      *(float4*)&Ws[i] = *(const float4*)&W1[i];
    __syncthreads();
    const int tx = tid & 31, ty = tid >> 5;
    float acc[4][4];
#pragma unroll
    for (int i = 0; i < 4; ++i)
#pragma unroll
      for (int jj = 0; jj < 4; ++jj) acc[i][jj] = 0.f;
    for (int k = 0; k < 80; ++k) {
      float av[4];
#pragma unroll
      for (int i = 0; i < 4; ++i) av[i] = As[(ty * 4 + i) * 80 + k];
      float4 bv = *(const float4*)&Ws[k * 128 + tx * 4];
      float bva[4] = {bv.x, bv.y, bv.z, bv.w};
#pragma unroll
      for (int i = 0; i < 4; ++i)
#pragma unroll
        for (int jj = 0; jj < 4; ++jj) acc[i][jj] = fmaf(av[i], bva[jj], acc[i][jj]);
    }
#pragma unroll
    for (int jj = 0; jj < 4; ++jj) {
      int g = dirb * 128 + tx * 4 + jj;
      ushort4 o;
      o.x = f2h(acc[0][jj]); o.y = f2h(acc[1][jj]);
      o.z = f2h(acc[2][jj]); o.w = f2h(acc[3][jj]);
      *(ushort4*)&Xf1[(size_t)g * 512 + m0 + ty * 4] = o;
    }
#pragma unroll
    for (int i = 0; i < 4; ++i) {
      ushort4 o;
      o.x = f2h(acc[i][0]); o.y = f2h(acc[i][1]);
      o.z = f2h(acc[i][2]); o.w = f2h(acc[i][3]);
      *(ushort4*)&Xr1N[((size_t)dirb * 512 + m0 + ty * 4 + i) * 128 + tx * 4] = o;
    }
  }
}

// ---------------------------------------------------------------------------
// Final out-layer elementwise: preds from Got fp16 (=G1h reuse), Xo16, sto.
// ---------------------------------------------------------------------------
__global__ __launch_bounds__(512) void outfinalk(
    const unsigned short* __restrict__ Got, const unsigned short* __restrict__ Xo16,
    const float* __restrict__ sto, const float* __restrict__ go,
    const float* __restrict__ eo, const float* __restrict__ bo,
    float* __restrict__ out0) {
  __shared__ float sst[256];
  const int tid = threadIdx.x;
  if (tid < 256) sst[tid] = sto[tid];
  __syncthreads();
  const int pos = (blockIdx.x * 512 + tid) * 4;   // over B*S*N = 524288
  const int b = pos >> 14, r = pos & 16383;
  const int t = r >> 9, n0 = r & 511;
  const int colb = b * 64 + t * 2;
  float outv[8];
#pragma unroll
  for (int p = 0; p < 2; ++p) {
    int ch0 = t * 2 + p, ch1 = 64 + t * 2 + p;
    float mean0 = sst[ch0] * (1.f / CNT_);
    float var0 = sst[128 + ch0] * (1.f / CNT_) - mean0 * mean0;
    float inv0 = rsqrtf(var0 + EPS_) * go[p];
    float mean1 = sst[ch1] * (1.f / CNT_);
    float var1 = sst[128 + ch1] * (1.f / CNT_) - mean1 * mean1;
    float inv1 = rsqrtf(var1 + EPS_) * go[p];
#pragma unroll
    for (int k = 0; k < 4; ++k) {
      float got0 = h2f(Got[(size_t)(n0 + k) * 4096 + colb + p]);
      float got1 = h2f(Got[(size_t)(n0 + k) * 4096 + 2048 + colb + p]);
      float h0 = h2f(Xo16[(size_t)(colb + p) * 512 + n0 + k]);
      float h1 = h2f(Xo16[(size_t)(2048 + colb + p) * 512 + n0 + k]);
      float o0 = fmaxf((got0 - mean0) * inv0 + eo[p], 0.f) + h0;
      float o1 = fmaxf((got1 - mean1) * inv1 + eo[p], 0.f) + h1;
      outv[k * 2 + p] = 0.5f * (o0 + o1) + bo[p];
    }
  }
  float4 v0; v0.x = outv[0]; v0.y = outv[1]; v0.z = outv[2]; v0.w = outv[3];
  float4 v1; v1.x = outv[4]; v1.y = outv[5]; v1.z = outv[6]; v1.w = outv[7];
  *(float4*)&out0[(size_t)pos * 2] = v0;
  *(float4*)&out0[(size_t)pos * 2 + 4] = v1;
}

// ---------------------------------------------------------------------------
extern "C" void kernel_launch(void* const* d_in, const int* in_sizes, int n_in,
                              void* d_out, int out_size, void* d_ws, size_t ws_size,
                              hipStream_t stream) {
  (void)in_sizes; (void)n_in; (void)out_size; (void)ws_size;
  const float* inp = (const float*)d_in[0];
  const float* inc = (const float*)d_in[1];
  const float* W1 = (const float*)d_in[2];
  const float* b1 = (const float*)d_in[3];
  const float* g1 = (const float*)d_in[4];
  const float* e1 = (const float*)d_in[5];
  const float* W2 = (const float*)d_in[6];
  const float* b2 = (const float*)d_in[7];
  const float* g2 = (const float*)d_in[8];
  const float* e2 = (const float*)d_in[9];
  const float* W0o = (const float*)d_in[10];
  const float* W1o = (const float*)d_in[11];
  const float* bo = (const float*)d_in[12];
  const float* go = (const float*)d_in[13];
  const float* eo = (const float*)d_in[14];

  // workspace layout; f32 region then fp16 region (~56 MB total)
  float* ws = (float*)d_ws;
  float* Hs   = ws;                  // 65536
  float* Hd   = Hs + 65536;          // 65536
  float* st1a = Hd + 65536;          // 512
  float* st1b = st1a + 512;          // 512
  float* st2  = st1b + 512;          // 256
  float* sto  = st2 + 256;           // 256 (pad stats block to 2048)
  float* after = st1a + 2048;
  unsigned short* Gh   = (unsigned short*)after;              // 512*512
  unsigned short* G1h  = Gh + 262144;                         // 512*8192
  unsigned short* G2h  = G1h + 4194304;                       // 512*4096
  unsigned short* Xf1  = G2h + 2097152;                       // 8192*512
  unsigned short* Xr1A = Xf1 + 4194304;                       // 32768*128
  unsigned short* Xr1B = Xr1A + 4194304;                      // 32768*128
  unsigned short* Xf2  = Xr1B + 4194304;                      // 4096*512
  unsigned short* Xr2  = Xf2 + 2097152;                       // 32768*64
  unsigned short* Xo16 = Xr2 + 2097152;                       // 4096*512
  unsigned short* Xh   = Xo16 + 2097152;                      // 64*512*64

  float* out0 = (float*)d_out;
  float* out1 = out0 + (size_t)B_ * S_ * N_ * 2;

  // Setup
  k_deg<<<1, 256, 0, stream>>>(inc, Hs, Hd);
  g_build<<<dim3(8, 8), 256, 0, stream>>>(Hd, Hs, Gh);
  prek<<<512, 512, 0, stream>>>(inp, W1, Xf1, Xr1A, Xh, st1a, sto);

  for (int ti = 0; ti < S_; ++ti) {
    const int tf = ti, tb = S_ - 1 - ti;
    float* stc = (ti & 1) ? st1b : st1a;
    float* stn = (ti & 1) ? st1a : st1b;
    unsigned short* xr1C = (ti & 1) ? Xr1B : Xr1A;
    unsigned short* xr1N = (ti & 1) ? Xr1A : Xr1B;
    const int doX1 = (ti < S_ - 1) ? 1 : 0;

    gmfma<<<dim3(128, 4), 256, 0, stream>>>(Gh, Xf1, G1h, 8192, stc,
                                            127, 64, 256, 128);
    cat2k<<<512, 512, 0, stream>>>(inp, Xh, W2, Xf2, Xr2, G1h, xr1C, stc,
                                   g1, e1, b1, st2, tf, tb);
    gmfma<<<dim3(64, 4), 256, 0, stream>>>(Gh, Xf2, G2h, 4096, st2,
                                           63, 32, 128, 64);
    eltk<<<512, 512, 0, stream>>>(inp, G1h, xr1C, stc, g1, e1, b1, G2h, Xr2,
                                  st2, g2, e2, b2, Xh, out1, W1, Xf1, xr1N,
                                  W0o, W1o, Xo16, tf, tb, doX1, stn);
  }

  // Batched out-layer: Got(fp16, reuse G1h) = G @ Xo, then elementwise preds.
  gmfma<<<dim3(64, 4), 256, 0, stream>>>(Gh, Xo16, G1h, 4096, sto,
                                         63, 32, 64, 128);
  outfinalk<<<256, 512, 0, stream>>>(G1h, Xo16, sto, go, eo, bo, out0);
}

// Round 12
// 2429.743 us; speedup vs baseline: 1.0143x; 1.0143x over previous
//
#include <hip/hip_runtime.h>
#include <math.h>

// Problem constants
#define B_   32
#define S_   32
#define N_   512
#define D_   16
#define H_   64
#define EPS_ 1e-5f
#define CNT_ 16384.0f     // B*N samples per batchnorm channel
#define SNH_ 1048576      // S*N*H (per-batch feats stride)
#define NH_  32768        // N*H
#define LDST 72           // padded LDS row stride (fp16 elems)
#define CAST 65           // padded cat2k As row stride (f32 elems)

typedef __attribute__((ext_vector_type(8))) short short8v;
typedef __attribute__((ext_vector_type(8))) _Float16 f16x8;
typedef __attribute__((ext_vector_type(4))) float f32x4;

__device__ __forceinline__ float sigm(float x) { return 1.0f / (1.0f + __expf(-x)); }

__device__ __forceinline__ unsigned short f2h(float x) {
  union { _Float16 h; unsigned short u; } c;
  c.h = (_Float16)x;
  return c.u;
}
__device__ __forceinline__ float h2f(unsigned short u) {
  union { _Float16 h; unsigned short u; } c;
  c.u = u;
  return (float)c.h;
}
// load 8 contiguous fp16 -> 8 floats
__device__ __forceinline__ void ld8h(const unsigned short* p, float* o) {
  f16x8 v = *(const f16x8*)p;
#pragma unroll
  for (int i = 0; i < 8; ++i) o[i] = (float)v[i];
}
// store 8 floats -> 8 contiguous fp16
__device__ __forceinline__ void st8h(unsigned short* p, const float* v) {
  short8v o;
#pragma unroll
  for (int i = 0; i < 8; ++i) ((unsigned short*)&o)[i] = f2h(v[i]);
  *(short8v*)p = o;
}

// ---------------------------------------------------------------------------
// Setup: degree factors from incidence H (512x128)
// ---------------------------------------------------------------------------
__global__ __launch_bounds__(256) void k_deg(const float* __restrict__ Hm,
                                             float* __restrict__ Hs,
                                             float* __restrict__ Hd) {
  __shared__ float sdv[512];
  __shared__ float sde[128];
  __shared__ float tmp[256];
  const int tid = threadIdx.x;
  const int e = tid & 127, half = tid >> 7;
  float p = 0.f;
  for (int r = 0; r < 256; ++r) p += Hm[(half * 256 + r) * 128 + e];
  tmp[tid] = p;
  for (int n = tid; n < 512; n += 256) {
    float s = 0.f;
    for (int k = 0; k < 128; k += 4) {
      float4 v = *(const float4*)&Hm[n * 128 + k];
      s += v.x + v.y + v.z + v.w;
    }
    sdv[n] = s;
  }
  __syncthreads();
  if (tid < 128) sde[tid] = tmp[tid] + tmp[tid + 128];
  __syncthreads();
  for (int i = tid; i < 512 * 128; i += 256) {
    int n = i >> 7, ee = i & 127;
    float hv = Hm[i];
    float hs = hv * rsqrtf(sdv[n]);
    Hs[i] = hs;
    Hd[i] = hs / sde[ee];
  }
}

// ---------------------------------------------------------------------------
// Setup: Gh (fp16) = Hd @ Hs^T  (512x512, K=128) — direct fp16 store.
// ---------------------------------------------------------------------------
__global__ __launch_bounds__(256) void g_build(const float* __restrict__ A,
                                               const float* __restrict__ B,
                                               unsigned short* __restrict__ Gh) {
  constexpr int KT = 16;
  __shared__ float As[KT][64];
  __shared__ float Bs[KT][64];
  const int tid = threadIdx.x;
  const int tx = tid & 15, ty = tid >> 4;
  const int n0 = blockIdx.x * 64, m0 = blockIdx.y * 64;
  float acc[4][4];
#pragma unroll
  for (int i = 0; i < 4; ++i)
#pragma unroll
    for (int j = 0; j < 4; ++j) acc[i][j] = 0.f;
  const int ra = tid >> 2, ca = (tid & 3) * 4;
  for (int k0 = 0; k0 < 128; k0 += KT) {
    {
      float4 v = *(const float4*)&A[(size_t)(m0 + ra) * 128 + k0 + ca];
      As[ca + 0][ra] = v.x; As[ca + 1][ra] = v.y;
      As[ca + 2][ra] = v.z; As[ca + 3][ra] = v.w;
    }
    {
      float4 v = *(const float4*)&B[(size_t)(n0 + ra) * 128 + k0 + ca];
      Bs[ca + 0][ra] = v.x; Bs[ca + 1][ra] = v.y;
      Bs[ca + 2][ra] = v.z; Bs[ca + 3][ra] = v.w;
    }
    __syncthreads();
#pragma unroll
    for (int kk = 0; kk < KT; ++kk) {
      float a[4], bv[4];
#pragma unroll
      for (int i = 0; i < 4; ++i) a[i] = As[kk][ty * 4 + i];
#pragma unroll
      for (int j = 0; j < 4; ++j) bv[j] = Bs[kk][tx * 4 + j];
#pragma unroll
      for (int i = 0; i < 4; ++i)
#pragma unroll
        for (int j = 0; j < 4; ++j) acc[i][j] = fmaf(a[i], bv[j], acc[i][j]);
    }
    __syncthreads();
  }
#pragma unroll
  for (int i = 0; i < 4; ++i)
#pragma unroll
    for (int j = 0; j < 4; ++j)
      Gh[(size_t)(m0 + ty * 4 + i) * 512 + n0 + tx * 4 + j] = f2h(acc[i][j]);
}

// ---------------------------------------------------------------------------
// Setup: convert W1 (80x128) and W2 (80x64) to fp16.
// ---------------------------------------------------------------------------
__global__ __launch_bounds__(512) void wcvt(const float* __restrict__ W1,
                                            const float* __restrict__ W2,
                                            unsigned short* __restrict__ W1h,
                                            unsigned short* __restrict__ W2h) {
  const int tid = threadIdx.x;
  for (int i = tid; i < 10240; i += 512) W1h[i] = f2h(W1[i]);
  for (int i = tid; i < 5120; i += 512) W2h[i] = f2h(W2[i]);
}

// ---------------------------------------------------------------------------
// fp16 MFMA GEMM: C[row][col] = sum_m A[row][m] * B[col][m].  C stored fp16.
// A = Gh (512x512), B = [col][m] fp16 (X^T). BM=128, BN=64, BK=64, 4 waves.
// Epilogue: fp16 C + per-channel BN sum/sumsq atomics (from f32 acc):
//   base = (colblk >= dirColblks) ? dirBase : 0 ; ch = col & chmask
// ---------------------------------------------------------------------------
__global__ __launch_bounds__(256) void gmfma(
    const unsigned short* __restrict__ A, const unsigned short* __restrict__ Bf,
    unsigned short* __restrict__ C, int Nt, float* __restrict__ stats,
    int chmask, int dirColblks, int dirBase, int sqOff) {
  __shared__ __align__(16) unsigned short As[128 * LDST];
  __shared__ __align__(16) unsigned short Bs[64 * LDST];
  const int tid = threadIdx.x;
  const int lane = tid & 63;
  const int w = tid >> 6, wr = w >> 1, wc = w & 1;
  const int l15 = lane & 15, l4 = lane >> 4;
  const int col0 = blockIdx.x * 64, n0 = blockIdx.y * 128;
  const int srow = tid >> 3, sch = (tid & 7) * 8;

  f32x4 acc[4][2];
#pragma unroll
  for (int mi = 0; mi < 4; ++mi)
#pragma unroll
    for (int ni = 0; ni < 2; ++ni) acc[mi][ni] = (f32x4)0.f;

  short8v pa[4], pb[2];
#pragma unroll
  for (int q = 0; q < 4; ++q)
    pa[q] = *(const short8v*)&A[(size_t)(n0 + srow + q * 32) * 512 + sch];
#pragma unroll
  for (int q = 0; q < 2; ++q)
    pb[q] = *(const short8v*)&Bf[(size_t)(col0 + srow + q * 32) * 512 + sch];

  for (int k0 = 0; k0 < 512; k0 += 64) {
#pragma unroll
    for (int q = 0; q < 4; ++q)
      *(short8v*)&As[(srow + q * 32) * LDST + sch] = pa[q];
#pragma unroll
    for (int q = 0; q < 2; ++q)
      *(short8v*)&Bs[(srow + q * 32) * LDST + sch] = pb[q];
    __syncthreads();
    if (k0 < 448) {
      int kn = k0 + 64;
#pragma unroll
      for (int q = 0; q < 4; ++q)
        pa[q] = *(const short8v*)&A[(size_t)(n0 + srow + q * 32) * 512 + kn + sch];
#pragma unroll
      for (int q = 0; q < 2; ++q)
        pb[q] = *(const short8v*)&Bf[(size_t)(col0 + srow + q * 32) * 512 + kn + sch];
    }
#pragma unroll
    for (int kk = 0; kk < 64; kk += 32) {
      f16x8 av[4], bv[2];
#pragma unroll
      for (int mi = 0; mi < 4; ++mi)
        av[mi] = *(const f16x8*)&As[(wr * 64 + mi * 16 + l15) * LDST + kk + l4 * 8];
#pragma unroll
      for (int ni = 0; ni < 2; ++ni)
        bv[ni] = *(const f16x8*)&Bs[(wc * 32 + ni * 16 + l15) * LDST + kk + l4 * 8];
#pragma unroll
      for (int mi = 0; mi < 4; ++mi)
#pragma unroll
        for (int ni = 0; ni < 2; ++ni)
          acc[mi][ni] = __builtin_amdgcn_mfma_f32_16x16x32_f16(av[mi], bv[ni],
                                                               acc[mi][ni], 0, 0, 0);
    }
    __syncthreads();
  }

  float cs[2] = {0.f, 0.f}, cq[2] = {0.f, 0.f};
#pragma unroll
  for (int mi = 0; mi < 4; ++mi)
#pragma unroll
    for (int ni = 0; ni < 2; ++ni)
#pragma unroll
      for (int r = 0; r < 4; ++r) {
        float val = acc[mi][ni][r];
        C[(size_t)(n0 + wr * 64 + mi * 16 + l4 * 4 + r) * Nt + col0 + wc * 32 + ni * 16 + l15] = f2h(val);
        cs[ni] += val;
        cq[ni] = fmaf(val, val, cq[ni]);
      }
  float* red = (float*)As;
  const int owner = wr * 4 + l4;
#pragma unroll
  for (int ni = 0; ni < 2; ++ni) {
    int cb = wc * 32 + ni * 16 + l15;
    red[cb * 8 + owner] = cs[ni];
    red[512 + cb * 8 + owner] = cq[ni];
  }
  __syncthreads();
  if (tid < 64) {
    float s = 0.f, q = 0.f;
    for (int o = 0; o < 8; ++o) { s += red[tid * 8 + o]; q += red[512 + tid * 8 + o]; }
    int base = (blockIdx.x >= dirColblks) ? dirBase : 0;
    int ch = (col0 + tid) & chmask;
    atomicAdd(&stats[base + ch], s);
    atomicAdd(&stats[base + sqOff + ch], q);
  }
}

// ---------------------------------------------------------------------------
// Pre: zero h (fp16), st1a, sto; X1(t0) = x @ W1[0:16] (h=0). Dual write fp16:
// col-major Xf1[col=dirb*128+d][m] + row-major Xr1A[(dirb*512+m)][d].
// ---------------------------------------------------------------------------
__global__ __launch_bounds__(512) void prek(
    const float* __restrict__ inp, const float* __restrict__ W1,
    unsigned short* __restrict__ Xf1, unsigned short* __restrict__ Xr1A,
    unsigned short* __restrict__ Xh, float* __restrict__ st1a,
    float* __restrict__ sto) {
  __shared__ float As[64 * 16];
  __shared__ float Ws[16 * 128];
  const int tid = threadIdx.x, bid = blockIdx.x;
  const int dirb = bid >> 3, m0 = (bid & 7) * 64;
  const int b = dirb & 31;
  const int t0 = (dirb < 32) ? 0 : (S_ - 1);
  *(short8v*)&Xh[((size_t)dirb * 512 + m0) * 64 + tid * 8] = (short8v)0;
  if (bid == 0) st1a[tid] = 0.f;
  if (bid == 1 && tid < 256) sto[tid] = 0.f;
  *(float4*)&Ws[tid * 4] = *(const float4*)&W1[tid * 4];
  {
    int row = tid >> 3, j = tid & 7;
    float2 iv = *(const float2*)&inp[(size_t)((b * S_ + t0) * N_ + m0 + row) * D_ + j * 2];
    As[row * 16 + j * 2] = iv.x;
    As[row * 16 + j * 2 + 1] = iv.y;
  }
  __syncthreads();
  const int tx = tid & 31, ty = tid >> 5;
  float acc[4][4];
#pragma unroll
  for (int i = 0; i < 4; ++i)
#pragma unroll
    for (int j = 0; j < 4; ++j) acc[i][j] = 0.f;
  for (int k = 0; k < 16; ++k) {
    float av[4];
#pragma unroll
    for (int i = 0; i < 4; ++i) av[i] = As[(ty * 4 + i) * 16 + k];
    float4 bv = *(const float4*)&Ws[k * 128 + tx * 4];
    float bva[4] = {bv.x, bv.y, bv.z, bv.w};
#pragma unroll
    for (int i = 0; i < 4; ++i)
#pragma unroll
      for (int j = 0; j < 4; ++j) acc[i][j] = fmaf(av[i], bva[j], acc[i][j]);
  }
#pragma unroll
  for (int j = 0; j < 4; ++j) {
    int g = dirb * 128 + tx * 4 + j;
    ushort4 o;
    o.x = f2h(acc[0][j]); o.y = f2h(acc[1][j]);
    o.z = f2h(acc[2][j]); o.w = f2h(acc[3][j]);
    *(ushort4*)&Xf1[(size_t)g * 512 + m0 + ty * 4] = o;
  }
#pragma unroll
  for (int i = 0; i < 4; ++i) {
    ushort4 o;
    o.x = f2h(acc[i][0]); o.y = f2h(acc[i][1]);
    o.z = f2h(acc[i][2]); o.w = f2h(acc[i][3]);
    *(ushort4*)&Xr1A[((size_t)dirb * 512 + m0 + ty * 4 + i) * 128 + tx * 4] = o;
  }
}

// ---------------------------------------------------------------------------
// cat2: X2 = cat(x_t, r*h) @ W2 with fused r-gate. Both dirs batched.
// h fp16 (Xh); residual x1 from row-major Xr1C. Dual write X2 (Xf2 + Xr2).
// As stride padded to CAST=65 (bank-conflict fix); W2 loaded fp16.
// ---------------------------------------------------------------------------
__global__ __launch_bounds__(512) void cat2k(
    const float* __restrict__ inp, const unsigned short* __restrict__ Xh,
    const unsigned short* __restrict__ W2h, unsigned short* __restrict__ Xf2,
    unsigned short* __restrict__ Xr2,
    const unsigned short* __restrict__ G1h, const unsigned short* __restrict__ Xr1C,
    const float* __restrict__ st1c, const float* __restrict__ g1,
    const float* __restrict__ e1, const float* __restrict__ b1,
    float* __restrict__ st2, int tf, int tb) {
  __shared__ float As[80 * CAST];   // [k][row], stride 65
  __shared__ float Ws[80 * 64];
  __shared__ float sm[128], sa[128], sb[128], sbb[128];
  const int tid = threadIdx.x, bid = blockIdx.x;
  const int dirb = bid >> 3, m0 = (bid & 7) * 64;
  const int b = dirb & 31;
  const int dir = (dirb >= 32);
  const int t = dir ? tb : tf;
  if (bid == 0 && tid < 256) st2[tid] = 0.f;
  const float* stp = st1c + (dir ? 256 : 0);
  if (tid < 128) {
    float mean = stp[tid] * (1.f / CNT_);
    float var = fmaf(stp[128 + tid], 1.f / CNT_, -mean * mean);
    float inv = rsqrtf(var + EPS_);
    sm[tid] = mean; sa[tid] = inv * g1[tid];
    sb[tid] = e1[tid]; sbb[tid] = b1[tid];
  }
  for (int i = tid * 8; i < 5120; i += 4096) {
    f16x8 v = *(const f16x8*)&W2h[i];
#pragma unroll
    for (int q = 0; q < 8; ++q) Ws[i + q] = (float)v[q];
  }
  __syncthreads();
  const int row = tid >> 3, j = tid & 7;
  const int m = m0 + row;
  if (j < 4) {
    float4 iv = *(const float4*)&inp[(size_t)((b * S_ + t) * N_ + m) * D_ + j * 4];
    As[(j * 4 + 0) * CAST + row] = iv.x; As[(j * 4 + 1) * CAST + row] = iv.y;
    As[(j * 4 + 2) * CAST + row] = iv.z; As[(j * 4 + 3) * CAST + row] = iv.w;
  }
  {
    const int c0 = j * 8;
    const int n = m >> 1;
    const int dd = ((m & 1) << 6) + c0;
    float hva[8], gva[8], xva[8];
    ld8h(&Xh[((size_t)dirb * 512 + m) * 64 + c0], hva);
    ld8h(&G1h[(size_t)n * 8192 + dirb * 128 + dd], gva);
    ld8h(&Xr1C[((size_t)dirb * 512 + n) * 128 + dd], xva);
#pragma unroll
    for (int i = 0; i < 8; ++i) {
      int d2 = dd + i;
      float pre = fmaf(gva[i] - sm[d2], sa[d2], sb[d2]);
      pre = fmaxf(pre, 0.f) + xva[i] + sbb[d2];
      As[(16 + c0 + i) * CAST + row] = sigm(pre) * hva[i];
    }
  }
  __syncthreads();
  const int tx = tid & 15, ty = tid >> 4;
  float acc[2][4];
#pragma unroll
  for (int i = 0; i < 2; ++i)
#pragma unroll
    for (int jj = 0; jj < 4; ++jj) acc[i][jj] = 0.f;
  for (int k = 0; k < 80; ++k) {
    float a0 = As[k * CAST + ty * 2], a1 = As[k * CAST + ty * 2 + 1];
    float4 bv = *(const float4*)&Ws[k * 64 + tx * 4];
    float bva[4] = {bv.x, bv.y, bv.z, bv.w};
#pragma unroll
    for (int jj = 0; jj < 4; ++jj) {
      acc[0][jj] = fmaf(a0, bva[jj], acc[0][jj]);
      acc[1][jj] = fmaf(a1, bva[jj], acc[1][jj]);
    }
  }
#pragma unroll
  for (int jj = 0; jj < 4; ++jj) {
    int g = dirb * 64 + tx * 4 + jj;
    ushort2 o;
    o.x = f2h(acc[0][jj]); o.y = f2h(acc[1][jj]);
    *(ushort2*)&Xf2[(size_t)g * 512 + m0 + ty * 2] = o;
  }
#pragma unroll
  for (int i = 0; i < 2; ++i) {
    ushort4 o;
    o.x = f2h(acc[i][0]); o.y = f2h(acc[i][1]);
    o.z = f2h(acc[i][2]); o.w = f2h(acc[i][3]);
    *(ushort4*)&Xr2[((size_t)dirb * 512 + m0 + ty * 2 + i) * 64 + tx * 4] = o;
  }
}

// ---------------------------------------------------------------------------
// elt: gates + h update (fp16) + [fwd] feats0 write (f32) + out-proj column
// store (fp16) + X1(nextT) projection (Xf1 col-major + Xr1N row-major).
// W1 loaded fp16.
// ---------------------------------------------------------------------------
__global__ __launch_bounds__(512) void eltk(
    const float* __restrict__ inp, const unsigned short* __restrict__ G1h,
    const unsigned short* __restrict__ Xr1C, const float* __restrict__ st1c,
    const float* __restrict__ g1, const float* __restrict__ e1,
    const float* __restrict__ b1, const unsigned short* __restrict__ G2h,
    const unsigned short* __restrict__ Xr2, const float* __restrict__ st2,
    const float* __restrict__ g2, const float* __restrict__ e2,
    const float* __restrict__ b2, unsigned short* __restrict__ Xh,
    float* __restrict__ out1, const unsigned short* __restrict__ W1h,
    unsigned short* __restrict__ Xf1, unsigned short* __restrict__ Xr1N,
    const float* __restrict__ W0o, const float* __restrict__ W1o,
    unsigned short* __restrict__ Xo16,
    int tf, int tb, int doX1, float* __restrict__ stn) {
  __shared__ float As[64 * 80];     // [row][k]: k<16 x_next, k>=16 hn
  __shared__ float Ws[80 * 128];
  __shared__ float sW0[128], sW1[128];
  const int tid = threadIdx.x, bid = blockIdx.x;
  const int dirb = bid >> 3, m0 = (bid & 7) * 64;
  const int b = dirb & 31;
  const int dir = (dirb >= 32);
  const int t = dir ? tb : tf;
  const int nextT = dir ? (tb - 1) : (tf + 1);
  if (bid == 0) stn[tid] = 0.f;
  if (tid < 128) { sW0[tid] = W0o[tid]; sW1[tid] = W1o[tid]; }
  __syncthreads();

  const int row = tid >> 3, co = (tid & 7) * 8;
  const int m = m0 + row;
  const int mh = m >> 1;
  const int du0 = ((m & 1) << 6) + co;
  const float* stp = st1c + (dir ? 256 : 0);
  const float* st2p = st2 + (dir ? 128 : 0);
  float g1a[8], g2a[8], ha[8], x1a[8], x2a[8];
  {
    ld8h(&Xh[((size_t)dirb * 512 + m) * 64 + co], ha);
    ld8h(&G1h[(size_t)(256 + mh) * 8192 + dirb * 128 + du0], g1a);
    ld8h(&G2h[(size_t)m * 4096 + dirb * 64 + co], g2a);
    ld8h(&Xr1C[((size_t)dirb * 512 + 256 + mh) * 128 + du0], x1a);
    ld8h(&Xr2[((size_t)dirb * 512 + m) * 64 + co], x2a);
  }
  float hn[8];
#pragma unroll
  for (int i = 0; i < 8; ++i) {
    int du = du0 + i;
    float mean = stp[du] * (1.f / CNT_);
    float var = stp[128 + du] * (1.f / CNT_) - mean * mean;
    float inv = rsqrtf(var + EPS_);
    float pre = fmaxf((g1a[i] - mean) * inv * g1[du] + e1[du], 0.f) + x1a[i] + b1[du];
    float u = sigm(pre);
    int dc = co + i;
    float mean2 = st2p[dc] * (1.f / CNT_);
    float var2 = st2p[64 + dc] * (1.f / CNT_) - mean2 * mean2;
    float inv2 = rsqrtf(var2 + EPS_);
    float pre2 = fmaxf((g2a[i] - mean2) * inv2 * g2[dc] + e2[dc], 0.f) + x2a[i] + b2[dc];
    float cc = tanhf(pre2);
    hn[i] = u * ha[i] + (1.f - u) * cc;
  }
  st8h(&Xh[((size_t)dirb * 512 + m) * 64 + co], hn);
  *(float4*)&As[row * 80 + 16 + co] = *(const float4*)&hn[0];
  *(float4*)&As[row * 80 + 16 + co + 4] = *(const float4*)&hn[4];
  if (!dir) {  // fwd: feats0 (f32 exact)
    float* po = &out1[(size_t)b * SNH_ + (size_t)t * NH_ + m * 64 + co];
    *(float4*)&po[0] = *(const float4*)&hn[0];
    *(float4*)&po[4] = *(const float4*)&hn[4];
  }
  {
    const float* sW = dir ? sW1 : sW0;
    float p0 = 0.f, p1 = 0.f;
#pragma unroll
    for (int jj = 0; jj < 8; ++jj) {
      int c = co + jj;
      p0 = fmaf(hn[jj], sW[c * 2], p0);
      p1 = fmaf(hn[jj], sW[c * 2 + 1], p1);
    }
#pragma unroll
    for (int off = 1; off < 8; off <<= 1) {
      p0 += __shfl_xor(p0, off);
      p1 += __shfl_xor(p1, off);
    }
    if ((tid & 7) == 0) {
      int colb = (dir ? 2048 : 0) + b * 64 + t * 2;
      Xo16[(size_t)colb * 512 + m] = f2h(p0);
      Xo16[(size_t)(colb + 1) * 512 + m] = f2h(p1);
    }
  }

  if (doX1) {
    {
      int ri = tid >> 3, k2 = (tid & 7) * 2;
      float2 iv = *(const float2*)&inp[(size_t)((b * S_ + nextT) * N_ + m0 + ri) * D_ + k2];
      As[ri * 80 + k2] = iv.x;
      As[ri * 80 + k2 + 1] = iv.y;
    }
    for (int i = tid * 8; i < 10240; i += 4096) {
      f16x8 v = *(const f16x8*)&W1h[i];
#pragma unroll
      for (int q = 0; q < 8; ++q) Ws[i + q] = (float)v[q];
    }
    __syncthreads();
    const int tx = tid & 31, ty = tid >> 5;
    float acc[4][4];
#pragma unroll
    for (int i = 0; i < 4; ++i)
#pragma unroll
      for (int jj = 0; jj < 4; ++jj) acc[i][jj] = 0.f;
    for (int k = 0; k < 80; ++k) {
      float av[4];
#pragma unroll
      for (int i = 0; i < 4; ++i) av[i] = As[(ty * 4 + i) * 80 + k];
      float4 bv = *(const float4*)&Ws[k * 128 + tx * 4];
      float bva[4] = {bv.x, bv.y, bv.z, bv.w};
#pragma unroll
      for (int i = 0; i < 4; ++i)
#pragma unroll
        for (int jj = 0; jj < 4; ++jj) acc[i][jj] = fmaf(av[i], bva[jj], acc[i][jj]);
    }
#pragma unroll
    for (int jj = 0; jj < 4; ++jj) {
      int g = dirb * 128 + tx * 4 + jj;
      ushort4 o;
      o.x = f2h(acc[0][jj]); o.y = f2h(acc[1][jj]);
      o.z = f2h(acc[2][jj]); o.w = f2h(acc[3][jj]);
      *(ushort4*)&Xf1[(size_t)g * 512 + m0 + ty * 4] = o;
    }
#pragma unroll
    for (int i = 0; i < 4; ++i) {
      ushort4 o;
      o.x = f2h(acc[i][0]); o.y = f2h(acc[i][1]);
      o.z = f2h(acc[i][2]); o.w = f2h(acc[i][3]);
      *(ushort4*)&Xr1N[((size_t)dirb * 512 + m0 + ty * 4 + i) * 128 + tx * 4] = o;
    }
  }
}

// ---------------------------------------------------------------------------
// Final out-layer elementwise: preds from Got fp16 (=G1h reuse), Xo16, sto.
// ---------------------------------------------------------------------------
__global__ __launch_bounds__(512) void outfinalk(
    const unsigned short* __restrict__ Got, const unsigned short* __restrict__ Xo16,
    const float* __restrict__ sto, const float* __restrict__ go,
    const float* __restrict__ eo, const float* __restrict__ bo,
    float* __restrict__ out0) {
  __shared__ float sst[256];
  const int tid = threadIdx.x;
  if (tid < 256) sst[tid] = sto[tid];
  __syncthreads();
  const int pos = (blockIdx.x * 512 + tid) * 4;   // over B*S*N = 524288
  const int b = pos >> 14, r = pos & 16383;
  const int t = r >> 9, n0 = r & 511;
  const int colb = b * 64 + t * 2;
  float outv[8];
#pragma unroll
  for (int p = 0; p < 2; ++p) {
    int ch0 = t * 2 + p, ch1 = 64 + t * 2 + p;
    float mean0 = sst[ch0] * (1.f / CNT_);
    float var0 = sst[128 + ch0] * (1.f / CNT_) - mean0 * mean0;
    float inv0 = rsqrtf(var0 + EPS_) * go[p];
    float mean1 = sst[ch1] * (1.f / CNT_);
    float var1 = sst[128 + ch1] * (1.f / CNT_) - mean1 * mean1;
    float inv1 = rsqrtf(var1 + EPS_) * go[p];
#pragma unroll
    for (int k = 0; k < 4; ++k) {
      float got0 = h2f(Got[(size_t)(n0 + k) * 4096 + colb + p]);
      float got1 = h2f(Got[(size_t)(n0 + k) * 4096 + 2048 + colb + p]);
      float h0 = h2f(Xo16[(size_t)(colb + p) * 512 + n0 + k]);
      float h1 = h2f(Xo16[(size_t)(2048 + colb + p) * 512 + n0 + k]);
      float o0 = fmaxf((got0 - mean0) * inv0 + eo[p], 0.f) + h0;
      float o1 = fmaxf((got1 - mean1) * inv1 + eo[p], 0.f) + h1;
      outv[k * 2 + p] = 0.5f * (o0 + o1) + bo[p];
    }
  }
  float4 v0; v0.x = outv[0]; v0.y = outv[1]; v0.z = outv[2]; v0.w = outv[3];
  float4 v1; v1.x = outv[4]; v1.y = outv[5]; v1.z = outv[6]; v1.w = outv[7];
  *(float4*)&out0[(size_t)pos * 2] = v0;
  *(float4*)&out0[(size_t)pos * 2 + 4] = v1;
}

// ---------------------------------------------------------------------------
extern "C" void kernel_launch(void* const* d_in, const int* in_sizes, int n_in,
                              void* d_out, int out_size, void* d_ws, size_t ws_size,
                              hipStream_t stream) {
  (void)in_sizes; (void)n_in; (void)out_size; (void)ws_size;
  const float* inp = (const float*)d_in[0];
  const float* inc = (const float*)d_in[1];
  const float* W1 = (const float*)d_in[2];
  const float* b1 = (const float*)d_in[3];
  const float* g1 = (const float*)d_in[4];
  const float* e1 = (const float*)d_in[5];
  const float* W2 = (const float*)d_in[6];
  const float* b2 = (const float*)d_in[7];
  const float* g2 = (const float*)d_in[8];
  const float* e2 = (const float*)d_in[9];
  const float* W0o = (const float*)d_in[10];
  const float* W1o = (const float*)d_in[11];
  const float* bo = (const float*)d_in[12];
  const float* go = (const float*)d_in[13];
  const float* eo = (const float*)d_in[14];

  // workspace layout; f32 region then fp16 region (~56 MB total)
  float* ws = (float*)d_ws;
  float* Hs   = ws;                  // 65536
  float* Hd   = Hs + 65536;          // 65536
  float* st1a = Hd + 65536;          // 512
  float* st1b = st1a + 512;          // 512
  float* st2  = st1b + 512;          // 256
  float* sto  = st2 + 256;           // 256 (pad stats block to 2048)
  float* after = st1a + 2048;
  unsigned short* Gh   = (unsigned short*)after;              // 512*512
  unsigned short* G1h  = Gh + 262144;                         // 512*8192
  unsigned short* G2h  = G1h + 4194304;                       // 512*4096
  unsigned short* Xf1  = G2h + 2097152;                       // 8192*512
  unsigned short* Xr1A = Xf1 + 4194304;                       // 32768*128
  unsigned short* Xr1B = Xr1A + 4194304;                      // 32768*128
  unsigned short* Xf2  = Xr1B + 4194304;                      // 4096*512
  unsigned short* Xr2  = Xf2 + 2097152;                       // 32768*64
  unsigned short* Xo16 = Xr2 + 2097152;                       // 4096*512
  unsigned short* Xh   = Xo16 + 2097152;                      // 64*512*64
  unsigned short* W1h  = Xh + 2097152;                        // 10240
  unsigned short* W2h  = W1h + 10240;                         // 5120

  float* out0 = (float*)d_out;
  float* out1 = out0 + (size_t)B_ * S_ * N_ * 2;

  // Setup
  k_deg<<<1, 256, 0, stream>>>(inc, Hs, Hd);
  g_build<<<dim3(8, 8), 256, 0, stream>>>(Hd, Hs, Gh);
  wcvt<<<1, 512, 0, stream>>>(W1, W2, W1h, W2h);
  prek<<<512, 512, 0, stream>>>(inp, W1, Xf1, Xr1A, Xh, st1a, sto);

  for (int ti = 0; ti < S_; ++ti) {
    const int tf = ti, tb = S_ - 1 - ti;
    float* stc = (ti & 1) ? st1b : st1a;
    float* stn = (ti & 1) ? st1a : st1b;
    unsigned short* xr1C = (ti & 1) ? Xr1B : Xr1A;
    unsigned short* xr1N = (ti & 1) ? Xr1A : Xr1B;
    const int doX1 = (ti < S_ - 1) ? 1 : 0;

    gmfma<<<dim3(128, 4), 256, 0, stream>>>(Gh, Xf1, G1h, 8192, stc,
                                            127, 64, 256, 128);
    cat2k<<<512, 512, 0, stream>>>(inp, Xh, W2h, Xf2, Xr2, G1h, xr1C, stc,
                                   g1, e1, b1, st2, tf, tb);
    gmfma<<<dim3(64, 4), 256, 0, stream>>>(Gh, Xf2, G2h, 4096, st2,
                                           63, 32, 128, 64);
    eltk<<<512, 512, 0, stream>>>(inp, G1h, xr1C, stc, g1, e1, b1, G2h, Xr2,
                                  st2, g2, e2, b2, Xh, out1, W1h, Xf1, xr1N,
                                  W0o, W1o, Xo16, tf, tb, doX1, stn);
  }

  // Batched out-layer: Got(fp16, reuse G1h) = G @ Xo, then elementwise preds.
  gmfma<<<dim3(64, 4), 256, 0, stream>>>(Gh, Xo16, G1h, 4096, sto,
                                         63, 32, 64, 128);
  outfinalk<<<256, 512, 0, stream>>>(G1h, Xo16, sto, go, eo, bo, out0);
}